// Round 6
// baseline (85.595 us; speedup 1.0000x reference)
//
#include <hip/hip_runtime.h>
#include <hip/hip_bf16.h>

// MiniBatchDiscrimination via bf16 MFMA (gfx950).
// x: [32,16,16,256] f32, T: [256,64,8] f32, out: [32,16,16,320] f32.
// Kernel 1 (pack_T): T [256k][512t] f32 -> fragments bf16 in d_ws:
//   Tf[(tt*8+kt)*64 + l] = {T[kt*32+(l>>4)*8+j][tt*16+(l&15)], j=0..7}.
//   (lane map idx16=l&15, k=(l>>4)*8+j works as A- or B-operand.)
// Kernel 2 (mbd_main): grid 1024 = (pixel, t-quarter), 256 threads:
//   passthrough quarter of x (warms L2) -> MFMA with A=Tf (from L2),
//   B=x loaded straight from global (contiguous per lane, no LDS staging,
//   no pre-MFMA barrier) -> park M^T into Mlds[n][t] -> one barrier ->
//   pairwise exp(-L1) -> coalesced o_b stores.

namespace {
constexpr int kN = 32;
constexpr int kHW = 256;
constexpr int kF = 256;          // GEMM K
constexpr int kOutRow = 320;
constexpr int kMstride = 136;    // ushorts/row: 128 + 8 pad
constexpr int kOstride = 24;     // floats/row in obuf
}

using frag_ab = __attribute__((ext_vector_type(8))) short;   // 8 bf16
using frag_cd = __attribute__((ext_vector_type(4))) float;   // 4 f32

__device__ inline unsigned short f2bf(float f) {
  union { __hip_bfloat16 h; unsigned short u; } c;
  c.h = __float2bfloat16(f);
  return c.u;
}

__device__ inline void unpack8(const uint4& m, float* f) {
  f[0] = __uint_as_float(m.x << 16);  f[1] = __uint_as_float(m.x & 0xffff0000u);
  f[2] = __uint_as_float(m.y << 16);  f[3] = __uint_as_float(m.y & 0xffff0000u);
  f[4] = __uint_as_float(m.z << 16);  f[5] = __uint_as_float(m.z & 0xffff0000u);
  f[6] = __uint_as_float(m.w << 16);  f[7] = __uint_as_float(m.w & 0xffff0000u);
}

__device__ inline uint4 pack_bf8(const float4& v0, const float4& v1) {
  uint4 p;
  p.x = (unsigned)f2bf(v0.x) | ((unsigned)f2bf(v0.y) << 16);
  p.y = (unsigned)f2bf(v0.z) | ((unsigned)f2bf(v0.w) << 16);
  p.z = (unsigned)f2bf(v1.x) | ((unsigned)f2bf(v1.y) << 16);
  p.w = (unsigned)f2bf(v1.z) | ((unsigned)f2bf(v1.w) << 16);
  return p;
}

// ---- Kernel 1: pack T into MFMA fragments (no LDS, no barriers) ----
__global__ __launch_bounds__(256)
void pack_T(const float* __restrict__ T, uint4* __restrict__ Tf) {
  const int g = blockIdx.x * 256 + threadIdx.x;  // 0..16383
  const int l = g & 63;
  const int frag = g >> 6;                       // 0..255 = tt*8 + kt
  const int tt = frag >> 3, kt = frag & 7;
  const int col = tt * 16 + (l & 15);
  const int k0 = kt * 32 + (l >> 4) * 8;
  unsigned p[4];
#pragma unroll
  for (int jj = 0; jj < 4; ++jj) {
    float a = T[(size_t)(k0 + jj * 2) * 512 + col];
    float b = T[(size_t)(k0 + jj * 2 + 1) * 512 + col];
    p[jj] = (unsigned)f2bf(a) | ((unsigned)f2bf(b) << 16);
  }
  Tf[g] = make_uint4(p[0], p[1], p[2], p[3]);
}

// ---- Kernel 2: fused GEMM + pairwise, one t-quarter per block ----
__global__ __launch_bounds__(256, 4)
void mbd_main(const float* __restrict__ x, const uint4* __restrict__ Tf,
              float* __restrict__ out) {
  __shared__ __align__(16) unsigned short Mlds[kN * kMstride];  // 8.7 KB
  __shared__ float obuf[kN * kOstride];                         // 3 KB
  const int hw = blockIdx.x & (kHW - 1);
  const int qg = blockIdx.x >> 8;          // t-quarter 0..3 (16 b's, 128 t-cols)
  const int tid = threadIdx.x;
  const int l = tid & 63, w = tid >> 6;    // 4 waves

  const float4* x4 = (const float4*)x;
  float4* out4 = (float4*)out;

  // Phase 0: passthrough this quarter's x features (coalesced; warms L2 with
  // exactly the rows the B-fragment loads below will hit).
  {
    const int n = tid >> 3;                // 0..31
    const int k8 = tid & 7;                // 8 groups of 8 floats = 64 features
    const size_t base = (size_t)(n * kHW + hw) * (kF / 4) + qg * 16 + k8 * 2;
    const size_t xb = (size_t)n * (kHW * kF / 4) + (size_t)hw * (kF / 4) +
                      qg * 16 + k8 * 2;
    float4 v0 = x4[xb];
    float4 v1 = x4[xb + 1];
    const size_t ob = (size_t)(n * kHW + hw) * (kOutRow / 4) + qg * 16 + k8 * 2;
    out4[ob] = v0;
    out4[ob + 1] = v1;
    (void)base;
  }

  // Phase 1: MFMA. A = Tf (t rows), B = x straight from global (n cols).
  // Wave w owns t-tiles qg*8 + {2w, 2w+1}; n-tiles 0,1. No barrier needed.
  frag_cd acc[2][2] = {};                  // [q][nt]
  // Per-lane x base: row n = nt*16 + (l&15), k-offset (l>>4)*8.
  const size_t xrow0 = ((size_t)((l & 15) + 0) * kHW + hw) * kF + (l >> 4) * 8;
  const size_t xrow1 = ((size_t)((l & 15) + 16) * kHW + hw) * kF + (l >> 4) * 8;
#pragma unroll
  for (int kt = 0; kt < 8; ++kt) {
    // B fragments: 8 contiguous floats per lane -> 2 dwordx4 each.
    float4 b00 = *(const float4*)&x[xrow0 + kt * 32];
    float4 b01 = *(const float4*)&x[xrow0 + kt * 32 + 4];
    float4 b10 = *(const float4*)&x[xrow1 + kt * 32];
    float4 b11 = *(const float4*)&x[xrow1 + kt * 32 + 4];
    uint4 bn0 = pack_bf8(b00, b01);
    uint4 bn1 = pack_bf8(b10, b11);
    frag_ab bf0 = __builtin_bit_cast(frag_ab, bn0);
    frag_ab bf1 = __builtin_bit_cast(frag_ab, bn1);
#pragma unroll
    for (int q = 0; q < 2; ++q) {
      const int tT = qg * 8 + w * 2 + q;   // global t-tile
      uint4 a = Tf[(tT * 8 + kt) * 64 + l];  // L2-hot, contiguous per wave
      frag_ab af = __builtin_bit_cast(frag_ab, a);
      acc[q][0] = __builtin_amdgcn_mfma_f32_16x16x32_bf16(af, bf0, acc[q][0], 0, 0, 0);
      acc[q][1] = __builtin_amdgcn_mfma_f32_16x16x32_bf16(af, bf1, acc[q][1], 0, 0, 0);
    }
  }

  // Phase 2: park M^T -> Mlds[n][t_local]. D[row=t][col=n]:
  // lane l holds rows (l>>4)*4+r, col l&15.
#pragma unroll
  for (int q = 0; q < 2; ++q)
#pragma unroll
    for (int nt = 0; nt < 2; ++nt)
#pragma unroll
      for (int r = 0; r < 4; ++r) {
        const int t = (w * 2 + q) * 16 + (l >> 4) * 4 + r;  // local col 0..127
        const int n = nt * 16 + (l & 15);
        Mlds[n * kMstride + t] = f2bf(acc[q][nt][r]);
      }
  __syncthreads();

  // Phase 3: pairwise exp(-L1). Thread: local b = tid>>4 (0..15), i in {i0,i0+1}.
  const int b = tid >> 4;
  const int i0 = (tid & 15) * 2;
  float mi[2][8];
#pragma unroll
  for (int ii = 0; ii < 2; ++ii) {
    uint4 m = *(const uint4*)&Mlds[(i0 + ii) * kMstride + b * 8];
    unpack8(m, mi[ii]);
  }
  float ob0 = 0.f, ob1 = 0.f;
#pragma unroll 4
  for (int j = 0; j < kN; ++j) {
    uint4 m = *(const uint4*)&Mlds[j * kMstride + b * 8];  // 16-lane broadcast
    float mj[8];
    unpack8(m, mj);
    float n0 = 0.f, n1 = 0.f;
#pragma unroll
    for (int c = 0; c < 8; ++c) {
      n0 += fabsf(mi[0][c] - mj[c]);
      n1 += fabsf(mi[1][c] - mj[c]);
    }
    ob0 += __expf(-n0);
    ob1 += __expf(-n1);
  }
  obuf[i0 * kOstride + b] = ob0;
  obuf[(i0 + 1) * kOstride + b] = ob1;
  __syncthreads();

  // Phase 4: coalesced o_b stores (32 n x 4 float4 per block).
  if (tid < 128) {
    const int n = tid >> 2;
    const int b4 = tid & 3;
    float4 v = *(const float4*)&obuf[n * kOstride + b4 * 4];
    out4[(size_t)(n * kHW + hw) * (kOutRow / 4) + (kF / 4) + qg * 4 + b4] = v;
  }
}

extern "C" void kernel_launch(void* const* d_in, const int* in_sizes, int n_in,
                              void* d_out, int out_size, void* d_ws, size_t ws_size,
                              hipStream_t stream) {
  const float* x = (const float*)d_in[0];     // [32,16,16,256]
  const float* T = (const float*)d_in[1];     // [256,64,8] = [256][512]
  float* out = (float*)d_out;                 // [32,16,16,320]
  uint4* Tf = (uint4*)d_ws;                   // 256 KB of fragments
  (void)in_sizes; (void)n_in; (void)out_size; (void)ws_size;
  pack_T<<<dim3(64), dim3(256), 0, stream>>>(T, Tf);
  mbd_main<<<dim3(4 * kHW), dim3(256), 0, stream>>>(x, Tf, out);
}